// Round 14
// baseline (3018.030 us; speedup 1.0000x reference)
//
#include <hip/hip_runtime.h>
#include <hip/hip_bf16.h>
#include <math.h>

#define NN   100000
#define EE   1000000
#define CCH  256      // context channels
#define DMC  128      // stage_metrics channels
#define HDC  192      // hidden of final transform
#define OUTC 128      // out channels
#define ET   64       // edges per k_edge_mlp tile; EE%ET==0
#define MS   132      // LDS msg-tile row stride (f32)
#define GS   391      // scan grid: ceil(NN/256)
#define PPK  114      // prep: pack blocks (114*4 = 456 frags)
#define PCV  12500    // prep: convert blocks (NN*DMC/4/256)
#define PHS  977      // prep: hist blocks (ceil(EE/4/256))
#define PGRID 768     // persistent k_edge_mlp grid (3 blocks/CU x 256)

typedef unsigned short u16;
using bf16x8 = __attribute__((ext_vector_type(8))) short;
using f32x4  = __attribute__((ext_vector_type(4))) float;
using u16x4  = __attribute__((ext_vector_type(4))) unsigned short;
using u16x8  = __attribute__((ext_vector_type(8))) unsigned short;

__device__ __forceinline__ float selu_f(float x) {
    const float sc = 1.0507009873554804934193349852946f;
    const float c1 = 1.7580993408473765792727863477367f;  // sc*alpha
    const float e = __expf(x);
    return x > 0.0f ? sc * x : __builtin_fmaf(c1, e, -c1);
}
__device__ __forceinline__ u16 f2bf(float f) {
    union { __hip_bfloat16 h; u16 u; } c;
    c.h = __float2bfloat16(f);
    return c.u;
}
__device__ __forceinline__ float bf2f(u16 h) {
    return __uint_as_float(((unsigned int)h) << 16);
}

// ---------------- K1: node transform as bf16 MFMA GEMM -------------------
__global__ __launch_bounds__(256, 2) void k_node_gemm(
    const float* __restrict__ ss, const float* __restrict__ se,
    const float* __restrict__ ctx, const u16* __restrict__ W0p,
    const float* __restrict__ bl, const float* __restrict__ br,
    u16* __restrict__ clb, u16* __restrict__ crb)
{
    __shared__ __align__(16) char Xs[64 * 512];  // [64][256] bf16 swizzled
    const int tid = threadIdx.x;
    const int wave = tid >> 6, lane = tid & 63;
    const int node0 = blockIdx.x * 64;

    {
        const int r = lane;
        const int nd = min(node0 + r, NN - 1);
#pragma unroll
        for (int i = 0; i < 8; ++i) {
            const int c0 = wave * 64 + i * 8;
            float4 va, vb;
            {
                const int c = c0;
                if (c < 16)       va = *reinterpret_cast<const float4*>(ss + nd * 16 + c);
                else if (c < 240) va = *reinterpret_cast<const float4*>(ctx + (size_t)nd * 224 + (c - 16));
                else              va = *reinterpret_cast<const float4*>(se + nd * 16 + (c - 240));
            }
            {
                const int c = c0 + 4;
                if (c < 16)       vb = *reinterpret_cast<const float4*>(ss + nd * 16 + c);
                else if (c < 240) vb = *reinterpret_cast<const float4*>(ctx + (size_t)nd * 224 + (c - 16));
                else              vb = *reinterpret_cast<const float4*>(se + nd * 16 + (c - 240));
            }
            u16x8 v;
            v[0] = f2bf(va.x); v[1] = f2bf(va.y); v[2] = f2bf(va.z); v[3] = f2bf(va.w);
            v[4] = f2bf(vb.x); v[5] = f2bf(vb.y); v[6] = f2bf(vb.z); v[7] = f2bf(vb.w);
            *reinterpret_cast<u16x8*>(Xs + r * 512 + ((c0 * 2) ^ ((r & 7) << 4))) = v;
        }
    }
    __syncthreads();

    const int r16   = lane & 15;
    const int khalf = (lane >> 4) << 4;
    const int rbase = (lane >> 4) * 4;

    f32x4 acc[4][8];
#pragma unroll
    for (int m = 0; m < 4; ++m)
#pragma unroll
        for (int jj = 0; jj < 8; ++jj) acc[m][jj] = (f32x4){0.f, 0.f, 0.f, 0.f};

    for (int ks = 0; ks < 8; ++ks) {
        bf16x8 b[8];
#pragma unroll
        for (int jj = 0; jj < 8; ++jj)
            b[jj] = *reinterpret_cast<const bf16x8*>(
                W0p + (((size_t)(wave + 4 * jj) * 8 + ks) * 64 + lane) * 8);
        const int kb = ks * 64 + khalf;
#pragma unroll
        for (int m = 0; m < 4; ++m) {
            const int row = m * 16 + r16;
            const bf16x8 a = *reinterpret_cast<const bf16x8*>(
                Xs + row * 512 + (kb ^ ((row & 7) << 4)));
#pragma unroll
            for (int jj = 0; jj < 8; ++jj)
                acc[m][jj] = __builtin_amdgcn_mfma_f32_16x16x32_bf16(a, b[jj], acc[m][jj], 0, 0, 0);
        }
    }

#pragma unroll
    for (int jj = 0; jj < 8; ++jj) {
        const int nt = wave + 4 * jj;            // wave-uniform branch
        const bool isL = nt < 16;
        const int ncl = (isL ? nt * 16 : (nt - 16) * 16) + r16;
        const float bias = isL ? bl[ncl] : br[ncl];
        u16* base = (isL ? clb : crb) + ncl;
#pragma unroll
        for (int m = 0; m < 4; ++m)
#pragma unroll
            for (int rr = 0; rr < 4; ++rr) {
                const int node = node0 + m * 16 + rbase + rr;
                if (node < NN)
                    base[(size_t)node * CCH] = f2bf(acc[m][jj][rr] + bias);
            }
    }
}

// ---------------- helpers for k_prep -------------------------------------
__device__ __forceinline__ void pack_frag(
    const float* __restrict__ W, u16* __restrict__ out, int K, int N,
    int f, int lane)
{
    const int KS = K >> 5;
    const int nt = f / KS, ks = f - nt * KS;
    const int n = nt * 16 + (lane & 15);
    const int k0 = ks * 32 + (lane >> 4) * 8;
    u16x8 v;
#pragma unroll
    for (int j = 0; j < 8; ++j) v[j] = f2bf(W[(size_t)(k0 + j) * N + n]);
    *reinterpret_cast<u16x8*>(out + ((size_t)f * 64 + lane) * 8) = v;
}

// ---------------- K_prep: fused weight-pack + metrics-convert + histogram
__global__ __launch_bounds__(256) void k_prep(
    const float* __restrict__ Wl, const float* __restrict__ Wr,
    const float* __restrict__ W1, const float* __restrict__ W2,
    const float* __restrict__ att, const float* __restrict__ met,
    const int* __restrict__ ei,
    u16* __restrict__ W0p, u16* __restrict__ W1p, u16* __restrict__ W2p,
    u16* __restrict__ attp, u16* __restrict__ metb, int* __restrict__ cnt)
{
    const int b = blockIdx.x, tid = threadIdx.x;
    if (b < PPK) {
        const int f = b * 4 + (tid >> 6);
        const int lane = tid & 63;
        if (f < 128)       pack_frag(Wl, W0p, CCH, CCH, f, lane);
        else if (f < 256)  pack_frag(Wr, W0p + (size_t)128 * 64 * 8, CCH, CCH, f - 128, lane);
        else if (f < 400)  pack_frag(W1, W1p, CCH + DMC, HDC, f - 256, lane);
        else if (f < 448)  pack_frag(W2, W2p, HDC, OUTC, f - 400, lane);
        else {
            const int ks = f - 448;
            const int nloc = lane & 15;
            const int k0 = ks * 32 + (lane >> 4) * 8;
            u16x8 v;
#pragma unroll
            for (int j = 0; j < 8; ++j) v[j] = f2bf((nloc == 0) ? att[k0 + j] : 0.f);
            *reinterpret_cast<u16x8*>(attp + ((size_t)ks * 64 + lane) * 8) = v;
        }
    } else if (b < PPK + PCV) {
        const int i = ((b - PPK) * 256 + tid) * 4;
        const float4 v = *reinterpret_cast<const float4*>(met + i);
        u16x4 o; o[0] = f2bf(v.x); o[1] = f2bf(v.y); o[2] = f2bf(v.z); o[3] = f2bf(v.w);
        *reinterpret_cast<u16x4*>(metb + i) = o;
    } else {
        const int i = (b - PPK - PCV) * 256 + tid;
        if (i < EE / 4) {
            const int4 d = *reinterpret_cast<const int4*>(ei + EE + i * 4);
            atomicAdd(&cnt[d.x], 1); atomicAdd(&cnt[d.y], 1);
            atomicAdd(&cnt[d.z], 1); atomicAdd(&cnt[d.w], 1);
        }
    }
}

// ---------------- Sort by dst: 3-phase scan -> scatter -------------------
__global__ __launch_bounds__(256) void k_scan1(
    const int* __restrict__ cnt, int* __restrict__ bsum)
{
    const int i = blockIdx.x * 256 + threadIdx.x;
    int v = (i < NN) ? cnt[i] : 0;
#pragma unroll
    for (int o = 1; o < 64; o <<= 1) v += __shfl_xor(v, o);
    __shared__ int ws[4];
    if ((threadIdx.x & 63) == 0) ws[threadIdx.x >> 6] = v;
    __syncthreads();
    if (threadIdx.x == 0) bsum[blockIdx.x] = ws[0] + ws[1] + ws[2] + ws[3];
}

__global__ __launch_bounds__(512) void k_scan2(int* __restrict__ bsum)
{
    __shared__ int s[512];
    const int t = threadIdx.x;
    const int v = (t < GS) ? bsum[t] : 0;
    s[t] = v;
    __syncthreads();
    for (int o = 1; o < 512; o <<= 1) {
        const int u = (t >= o) ? s[t - o] : 0;
        __syncthreads();
        s[t] += u;
        __syncthreads();
    }
    if (t < GS) bsum[t] = s[t] - v;             // exclusive
}

__global__ __launch_bounds__(256) void k_scan3(
    const int* __restrict__ cnt, const int* __restrict__ bsum,
    int* __restrict__ cur)
{
    const int t = threadIdx.x;
    const int i = blockIdx.x * 256 + t;
    const int lane = t & 63, w = t >> 6;
    const int v = (i < NN) ? cnt[i] : 0;
    int x = v;
#pragma unroll
    for (int o = 1; o < 64; o <<= 1) {
        const int u = __shfl_up(x, o);
        if (lane >= o) x += u;
    }
    __shared__ int wsum[4];
    if (lane == 63) wsum[w] = x;
    __syncthreads();
    int off = bsum[blockIdx.x];
    for (int k2 = 0; k2 < w; ++k2) off += wsum[k2];
    if (i < NN) cur[i] = off + x - v;           // exclusive prefix
}

__global__ __launch_bounds__(256) void k_scatter(
    const int* __restrict__ ei, int* __restrict__ cur, int2* __restrict__ sd)
{
    const int i = blockIdx.x * 256 + threadIdx.x;
    if (i < EE) {
        const int d = ei[EE + i];
        const int pos = atomicAdd(&cur[d], 1);
        sd[pos] = make_int2(ei[i], d);
    }
}

// ---------------- K3: persistent fused MLP with src-gather pipeline ------
// grid=768 (3 blocks/CU), grid-stride over EE/ET tiles. Per iteration:
// consume prefetched lv/mv (src gathers) + in-place rv (dst, L2-local) ->
// X-store; fetch next tile's (src,dst) list; barrier; ISSUE next src
// gathers (regs, fly under GEMM1/2 -- __syncthreads does not drain
// reg-destined global loads); GEMM1+alpha; H; GEMM2; seg-reduced epilogue.
__global__ __launch_bounds__(512, 6) void k_edge_mlp(
    const int2* __restrict__ sd,
    const u16* __restrict__ clb, const u16* __restrict__ crb,
    const u16* __restrict__ metb, const u16* __restrict__ attp,
    float* __restrict__ sb,
    const u16* __restrict__ W1p, const float* __restrict__ b1,
    const u16* __restrict__ W2p, const float* __restrict__ b2,
    float* __restrict__ dout)
{
    __shared__ __align__(16) char Xs[ET * 768];   // X [64][384]bf16 / H / msg
    __shared__ int edD[2][ET];                    // ping-pong dst list
    __shared__ int esN[ET], flg[ET];
    __shared__ float exs[ET];

    const int tid  = threadIdx.x;
    const int wave = tid >> 6;
    const int lane = tid & 63;
    const int wm = wave >> 2, wn = wave & 3;
    const int r16   = lane & 15;
    const int khalf = (lane >> 4) << 4;
    const int rbase = (lane >> 4) * 4;
    const int NT = EE / ET;
    const int stride = (int)gridDim.x;

    int T = blockIdx.x;
    int buf = 0;

    // ---- prologue: pair list + src gathers for first tile
    if (tid < ET) {
        const int2 p = sd[(size_t)T * ET + tid];
        esN[tid] = p.x;
        edD[0][tid] = p.y;
    }
    __syncthreads();

    u16x8 lv[4], mv[2];
#pragma unroll
    for (int i = 0; i < 4; ++i) {
        const int k = tid + i * 512;
        lv[i] = *reinterpret_cast<const u16x8*>(clb + (size_t)esN[k >> 5] * CCH + (k & 31) * 8);
    }
#pragma unroll
    for (int i = 0; i < 2; ++i) {
        const int k = tid + i * 512;
        mv[i] = *reinterpret_cast<const u16x8*>(metb + (size_t)esN[k >> 4] * DMC + (k & 15) * 8);
    }

    for (; T < NT; T += stride) {
        const int Tn = T + stride;

        // ---- X-store: ctx = selu(rv + lv) (rv loaded in place, dst-local)
#pragma unroll
        for (int i = 0; i < 4; ++i) {
            const int k = tid + i * 512;
            const int t = k >> 5, c = k & 31;
            const u16x8 rv = *reinterpret_cast<const u16x8*>(
                crb + (size_t)edD[buf][t] * CCH + c * 8);
            u16x8 v;
#pragma unroll
            for (int j = 0; j < 8; ++j) v[j] = f2bf(selu_f(bf2f(rv[j]) + bf2f(lv[i][j])));
            *reinterpret_cast<u16x8*>(Xs + t * 768 + ((c * 16) ^ ((t & 7) << 4))) = v;
        }
        // ---- met store + flg ballot
#pragma unroll
        for (int i = 0; i < 2; ++i) {
            const int k = tid + i * 512;
            const int t = k >> 4, g = k & 15;
            unsigned ob = 0;
#pragma unroll
            for (int j = 0; j < 8; ++j) ob |= (unsigned)mv[i][j];
            const bool nz = (ob & 0x7fffu) != 0u;
            const unsigned long long bal = __ballot(nz);
            if ((lane & 15) == 0)
                flg[t] = (int)((bal >> ((lane >> 4) * 16)) & 0xFFFFull) != 0;
            *reinterpret_cast<u16x8*>(Xs + t * 768 + (((32 + g) * 16) ^ ((t & 7) << 4))) = mv[i];
        }
        // ---- fetch next tile's pair list
        if (Tn < NT && tid < ET) {
            const int2 p = sd[(size_t)Tn * ET + tid];
            esN[tid] = p.x;
            edD[buf ^ 1][tid] = p.y;
        }
        __syncthreads();   // X ready; esN/edD[buf^1] ready

        // ---- issue next tile's src gathers (fly under the GEMMs)
        if (Tn < NT) {
#pragma unroll
            for (int i = 0; i < 4; ++i) {
                const int k = tid + i * 512;
                lv[i] = *reinterpret_cast<const u16x8*>(
                    clb + (size_t)esN[k >> 5] * CCH + (k & 31) * 8);
            }
#pragma unroll
            for (int i = 0; i < 2; ++i) {
                const int k = tid + i * 512;
                mv[i] = *reinterpret_cast<const u16x8*>(
                    metb + (size_t)esN[k >> 4] * DMC + (k & 15) * 8);
            }
        }

        // ---- GEMM1: H = selu(X @ W1 + b1); + alpha tile on wn==0 waves
        f32x4 acc[2][3];
        f32x4 acc3[2];
#pragma unroll
        for (int m = 0; m < 2; ++m) {
#pragma unroll
            for (int j = 0; j < 3; ++j) acc[m][j] = (f32x4){0.f, 0.f, 0.f, 0.f};
            acc3[m] = (f32x4){0.f, 0.f, 0.f, 0.f};
        }

        for (int ks = 0; ks < 12; ++ks) {
            bf16x8 b[3];
#pragma unroll
            for (int j = 0; j < 3; ++j)
                b[j] = *reinterpret_cast<const bf16x8*>(
                    W1p + (((size_t)(wn + 4 * j) * 12 + ks) * 64 + lane) * 8);
            bf16x8 b3 = {};
            const bool doA = (wn == 0) && (ks < 8);
            if (doA)
                b3 = *reinterpret_cast<const bf16x8*>(attp + ((size_t)ks * 64 + lane) * 8);
            const int kb = ks * 64 + khalf;
#pragma unroll
            for (int m = 0; m < 2; ++m) {
                const int row = (wm * 2 + m) * 16 + r16;
                const bf16x8 a = *reinterpret_cast<const bf16x8*>(
                    Xs + row * 768 + (kb ^ ((row & 7) << 4)));
#pragma unroll
                for (int j = 0; j < 3; ++j)
                    acc[m][j] = __builtin_amdgcn_mfma_f32_16x16x32_bf16(a, b[j], acc[m][j], 0, 0, 0);
                if (doA)
                    acc3[m] = __builtin_amdgcn_mfma_f32_16x16x32_bf16(a, b3, acc3[m], 0, 0, 0);
            }
        }

        // alpha extraction: col 0 of att tile -> lanes with (lane&15)==0
        if (wn == 0 && r16 == 0) {
            const int hi = lane >> 4;
#pragma unroll
            for (int m = 0; m < 2; ++m)
#pragma unroll
                for (int r = 0; r < 4; ++r) {
                    const int e = (wm * 2 + m) * 16 + hi * 4 + r;
                    const float al = acc3[m][r];
                    exs[e] = (flg[e] && al != 0.f) ? __expf(al) : 0.f;
                }
        }
        __syncthreads();   // X consumed; exs written

        // ---- write H (bf16, swizzled, row stride 384B)
#pragma unroll
        for (int j = 0; j < 3; ++j) {
            const int n = (wn + 4 * j) * 16 + r16;
            const float bb = b1[n];
#pragma unroll
            for (int m = 0; m < 2; ++m)
#pragma unroll
                for (int r = 0; r < 4; ++r) {
                    const int row = (wm * 2 + m) * 16 + rbase + r;
                    *reinterpret_cast<u16*>(Xs + row * 384 + ((n * 2) ^ ((row & 7) << 4))) =
                        f2bf(selu_f(acc[m][j][r] + bb));
                }
        }
        __syncthreads();

        // ---- GEMM2: F = selu(H @ W2 + b2)
        f32x4 acc2[2][2];
#pragma unroll
        for (int m = 0; m < 2; ++m)
#pragma unroll
            for (int j = 0; j < 2; ++j) acc2[m][j] = (f32x4){0.f, 0.f, 0.f, 0.f};

        for (int ks = 0; ks < 6; ++ks) {
            bf16x8 b[2];
#pragma unroll
            for (int j = 0; j < 2; ++j)
                b[j] = *reinterpret_cast<const bf16x8*>(
                    W2p + (((size_t)(wn + 4 * j) * 6 + ks) * 64 + lane) * 8);
            const int kb = ks * 64 + khalf;
#pragma unroll
            for (int m = 0; m < 2; ++m) {
                const int row = (wm * 2 + m) * 16 + r16;
                const bf16x8 a = *reinterpret_cast<const bf16x8*>(
                    Xs + row * 384 + (kb ^ ((row & 7) << 4)));
#pragma unroll
                for (int j = 0; j < 2; ++j)
                    acc2[m][j] = __builtin_amdgcn_mfma_f32_16x16x32_bf16(a, b[j], acc2[m][j], 0, 0, 0);
            }
        }
        __syncthreads();   // H reads done; Xs reused as msg tile

        // ---- epilogue: msg tile to LDS, dst-segment reduce (sorted rows)
        float* Ms = (float*)Xs;                   // [ET][MS] f32
#pragma unroll
        for (int j = 0; j < 2; ++j) {
            const int n = (wn + 4 * j) * 16 + r16;
            const float bb = b2[n];
#pragma unroll
            for (int m = 0; m < 2; ++m)
#pragma unroll
                for (int r = 0; r < 4; ++r) {
                    const int e = (wm * 2 + m) * 16 + rbase + r;
                    Ms[e * MS + n] = selu_f(acc2[m][j][r] + bb) * exs[e];
                }
        }
        __syncthreads();

        {
            const int col = tid & 127;
            const int h = tid >> 7;               // 0..3: rows [h*16, h*16+16)
            const int r0 = h * 16;
            int cur_d = edD[buf][r0];
            float s = Ms[r0 * MS + col];
            for (int r = r0 + 1; r < r0 + 16; ++r) {
                const int d = edD[buf][r];
                const float v = Ms[r * MS + col];
                if (d != cur_d) {
                    if (s != 0.f) atomicAdd(&dout[(size_t)cur_d * OUTC + col], s);
                    cur_d = d; s = v;
                } else {
                    s += v;
                }
            }
            if (s != 0.f) atomicAdd(&dout[(size_t)cur_d * OUTC + col], s);
        }
        if (tid < 4) {                            // ex segment-reduce -> sb
            const int r0 = tid * 16;
            int cur_d = edD[buf][r0];
            float s = exs[r0];
            for (int r = r0 + 1; r < r0 + 16; ++r) {
                const int d = edD[buf][r];
                const float v = exs[r];
                if (d != cur_d) {
                    if (s != 0.f) atomicAdd(&sb[cur_d], s);
                    cur_d = d; s = v;
                } else {
                    s += v;
                }
            }
            if (s != 0.f) atomicAdd(&sb[cur_d], s);
        }
        __syncthreads();   // Xs + edD[buf] free for next iteration
        buf ^= 1;
    }
}

// ---------------- K4: finalize: divide by sum, overwrite-or-sigmoid ------
__global__ __launch_bounds__(256) void k_finalize(
    float* __restrict__ dout, const float* __restrict__ met,
    const float* __restrict__ bias, const float* __restrict__ sb)
{
    const int n = blockIdx.x * 4 + (threadIdx.x >> 6);
    const int lane = threadIdx.x & 63;
    const float a0 = dout[(size_t)n * OUTC + lane];
    const float a1 = dout[(size_t)n * OUTC + 64 + lane];
    const bool ovr = __all((a0 == 0.f) && (a1 == 0.f));
    float r0, r1;
    if (ovr) {
        r0 = met[(size_t)n * DMC + lane];
        r1 = met[(size_t)n * DMC + 64 + lane];
    } else {
        const float inv = 1.0f / (sb[n] + 1e-16f);
        r0 = 1.f / (1.f + __expf(-(a0 * inv + bias[lane])));
        r1 = 1.f / (1.f + __expf(-(a1 * inv + bias[64 + lane])));
    }
    dout[(size_t)n * OUTC + lane] = r0;
    dout[(size_t)n * OUTC + 64 + lane] = r1;
}

extern "C" void kernel_launch(void* const* d_in, const int* in_sizes, int n_in,
                              void* d_out, int out_size, void* d_ws, size_t ws_size,
                              hipStream_t stream)
{
    const int*   ei   = (const int*)d_in[0];
    const float* ss   = (const float*)d_in[1];
    const float* se   = (const float*)d_in[2];
    const float* ctx  = (const float*)d_in[3];
    const float* met  = (const float*)d_in[4];
    const float* Wl   = (const float*)d_in[5];
    const float* bl   = (const float*)d_in[6];
    const float* Wr   = (const float*)d_in[7];
    const float* br   = (const float*)d_in[8];
    const float* att  = (const float*)d_in[9];
    const float* W1   = (const float*)d_in[10];
    const float* b1   = (const float*)d_in[11];
    const float* W2   = (const float*)d_in[12];
    const float* b2   = (const float*)d_in[13];
    const float* bias = (const float*)d_in[14];

    u16* clb  = (u16*)d_ws;
    u16* crb  = clb  + (size_t)NN * CCH;
    u16* metb = crb  + (size_t)NN * CCH;
    u16* W1p  = metb + (size_t)NN * DMC;
    u16* W2p  = W1p  + (size_t)(CCH + DMC) * HDC;
    u16* W0p  = W2p  + (size_t)HDC * OUTC;
    float* sb = (float*)(W0p + (size_t)CCH * 512);
    int* cnt  = (int*)(sb + NN);      // adjacent to sb: one fused memset
    int* cur  = cnt + NN;
    int2* sd  = (int2*)(cur + NN);
    int* bsum = (int*)(sd + EE);
    u16* attp = (u16*)(bsum + 512);

    float* dout = (float*)d_out;

    hipMemsetAsync(dout, 0, (size_t)NN * OUTC * sizeof(float), stream);
    hipMemsetAsync(sb, 0, (size_t)NN * 2 * sizeof(float), stream);  // sb + cnt

    // fused pack + convert + histogram
    k_prep<<<PPK + PCV + PHS, 256, 0, stream>>>(Wl, Wr, W1, W2, att, met, ei,
                                                W0p, W1p, W2p, attp, metb, cnt);

    // dst-sort: coalesced 3-phase scan -> scatter packed pairs
    k_scan1<<<GS, 256, 0, stream>>>(cnt, bsum);
    k_scan2<<<1, 512, 0, stream>>>(bsum);
    k_scan3<<<GS, 256, 0, stream>>>(cnt, bsum, cur);
    k_scatter<<<(EE + 255) / 256, 256, 0, stream>>>(ei, cur, sd);

    k_node_gemm<<<(NN + 63) / 64, 256, 0, stream>>>(ss, se, ctx, W0p, bl, br, clb, crb);
    k_edge_mlp<<<PGRID, 512, 0, stream>>>(sd, clb, crb, metb, attp, sb,
                                          W1p, b1, W2p, b2, dout);
    k_finalize<<<NN / 4, 256, 0, stream>>>(dout, met, bias, sb);
}

// Round 15
// 674.662 us; speedup vs baseline: 4.4734x; 4.4734x over previous
//
#include <hip/hip_runtime.h>
#include <hip/hip_bf16.h>
#include <math.h>

#define NN   100000
#define EE   1000000
#define CCH  256      // context channels
#define DMC  128      // stage_metrics channels
#define HDC  192      // hidden of final transform
#define OUTC 128      // out channels
#define ET   64       // edges per k_edge_mlp block (4 m-tiles); EE%ET==0
#define MS   132      // LDS msg-tile row stride (128 cols + ex col 128)
#define GS   391      // scan grid: ceil(NN/256)
#define PPK  114      // prep: pack blocks (114*4 = 456 frags)
#define PCV  12500    // prep: convert blocks (NN*DMC/4/256)
#define PHS  977      // prep: hist blocks (ceil(EE/4/256))

typedef unsigned short u16;
using bf16x8 = __attribute__((ext_vector_type(8))) short;
using f32x4  = __attribute__((ext_vector_type(4))) float;
using u16x4  = __attribute__((ext_vector_type(4))) unsigned short;
using u16x8  = __attribute__((ext_vector_type(8))) unsigned short;

__device__ __forceinline__ float selu_f(float x) {
    const float sc = 1.0507009873554804934193349852946f;
    const float c1 = 1.7580993408473765792727863477367f;  // sc*alpha
    const float e = __expf(x);
    return x > 0.0f ? sc * x : __builtin_fmaf(c1, e, -c1);
}
__device__ __forceinline__ u16 f2bf(float f) {
    union { __hip_bfloat16 h; u16 u; } c;
    c.h = __float2bfloat16(f);
    return c.u;
}
__device__ __forceinline__ float bf2f(u16 h) {
    return __uint_as_float(((unsigned int)h) << 16);
}

// ---------------- K1: node transform as bf16 MFMA GEMM -------------------
__global__ __launch_bounds__(256, 2) void k_node_gemm(
    const float* __restrict__ ss, const float* __restrict__ se,
    const float* __restrict__ ctx, const u16* __restrict__ W0p,
    const float* __restrict__ bl, const float* __restrict__ br,
    u16* __restrict__ clb, u16* __restrict__ crb)
{
    __shared__ __align__(16) char Xs[64 * 512];  // [64][256] bf16 swizzled
    const int tid = threadIdx.x;
    const int wave = tid >> 6, lane = tid & 63;
    const int node0 = blockIdx.x * 64;

    {
        const int r = lane;
        const int nd = min(node0 + r, NN - 1);
#pragma unroll
        for (int i = 0; i < 8; ++i) {
            const int c0 = wave * 64 + i * 8;
            float4 va, vb;
            {
                const int c = c0;
                if (c < 16)       va = *reinterpret_cast<const float4*>(ss + nd * 16 + c);
                else if (c < 240) va = *reinterpret_cast<const float4*>(ctx + (size_t)nd * 224 + (c - 16));
                else              va = *reinterpret_cast<const float4*>(se + nd * 16 + (c - 240));
            }
            {
                const int c = c0 + 4;
                if (c < 16)       vb = *reinterpret_cast<const float4*>(ss + nd * 16 + c);
                else if (c < 240) vb = *reinterpret_cast<const float4*>(ctx + (size_t)nd * 224 + (c - 16));
                else              vb = *reinterpret_cast<const float4*>(se + nd * 16 + (c - 240));
            }
            u16x8 v;
            v[0] = f2bf(va.x); v[1] = f2bf(va.y); v[2] = f2bf(va.z); v[3] = f2bf(va.w);
            v[4] = f2bf(vb.x); v[5] = f2bf(vb.y); v[6] = f2bf(vb.z); v[7] = f2bf(vb.w);
            *reinterpret_cast<u16x8*>(Xs + r * 512 + ((c0 * 2) ^ ((r & 7) << 4))) = v;
        }
    }
    __syncthreads();

    const int r16   = lane & 15;
    const int khalf = (lane >> 4) << 4;
    const int rbase = (lane >> 4) * 4;

    f32x4 acc[4][8];
#pragma unroll
    for (int m = 0; m < 4; ++m)
#pragma unroll
        for (int jj = 0; jj < 8; ++jj) acc[m][jj] = (f32x4){0.f, 0.f, 0.f, 0.f};

    for (int ks = 0; ks < 8; ++ks) {
        bf16x8 b[8];
#pragma unroll
        for (int jj = 0; jj < 8; ++jj)
            b[jj] = *reinterpret_cast<const bf16x8*>(
                W0p + (((size_t)(wave + 4 * jj) * 8 + ks) * 64 + lane) * 8);
        const int kb = ks * 64 + khalf;
#pragma unroll
        for (int m = 0; m < 4; ++m) {
            const int row = m * 16 + r16;
            const bf16x8 a = *reinterpret_cast<const bf16x8*>(
                Xs + row * 512 + (kb ^ ((row & 7) << 4)));
#pragma unroll
            for (int jj = 0; jj < 8; ++jj)
                acc[m][jj] = __builtin_amdgcn_mfma_f32_16x16x32_bf16(a, b[jj], acc[m][jj], 0, 0, 0);
        }
    }

#pragma unroll
    for (int jj = 0; jj < 8; ++jj) {
        const int nt = wave + 4 * jj;            // wave-uniform branch
        const bool isL = nt < 16;
        const int ncl = (isL ? nt * 16 : (nt - 16) * 16) + r16;
        const float bias = isL ? bl[ncl] : br[ncl];
        u16* base = (isL ? clb : crb) + ncl;
#pragma unroll
        for (int m = 0; m < 4; ++m)
#pragma unroll
            for (int rr = 0; rr < 4; ++rr) {
                const int node = node0 + m * 16 + rbase + rr;
                if (node < NN)
                    base[(size_t)node * CCH] = f2bf(acc[m][jj][rr] + bias);
            }
    }
}

// ---------------- helpers for k_prep -------------------------------------
__device__ __forceinline__ void pack_frag(
    const float* __restrict__ W, u16* __restrict__ out, int K, int N,
    int f, int lane)
{
    const int KS = K >> 5;
    const int nt = f / KS, ks = f - nt * KS;
    const int n = nt * 16 + (lane & 15);
    const int k0 = ks * 32 + (lane >> 4) * 8;
    u16x8 v;
#pragma unroll
    for (int j = 0; j < 8; ++j) v[j] = f2bf(W[(size_t)(k0 + j) * N + n]);
    *reinterpret_cast<u16x8*>(out + ((size_t)f * 64 + lane) * 8) = v;
}

// ---------------- K_prep: fused weight-pack + metrics-convert + histogram
__global__ __launch_bounds__(256) void k_prep(
    const float* __restrict__ Wl, const float* __restrict__ Wr,
    const float* __restrict__ W1, const float* __restrict__ W2,
    const float* __restrict__ att, const float* __restrict__ met,
    const int* __restrict__ ei,
    u16* __restrict__ W0p, u16* __restrict__ W1p, u16* __restrict__ W2p,
    u16* __restrict__ attp, u16* __restrict__ metb, int* __restrict__ cnt)
{
    const int b = blockIdx.x, tid = threadIdx.x;
    if (b < PPK) {
        const int f = b * 4 + (tid >> 6);
        const int lane = tid & 63;
        if (f < 128)       pack_frag(Wl, W0p, CCH, CCH, f, lane);
        else if (f < 256)  pack_frag(Wr, W0p + (size_t)128 * 64 * 8, CCH, CCH, f - 128, lane);
        else if (f < 400)  pack_frag(W1, W1p, CCH + DMC, HDC, f - 256, lane);
        else if (f < 448)  pack_frag(W2, W2p, HDC, OUTC, f - 400, lane);
        else {
            const int ks = f - 448;
            const int nloc = lane & 15;
            const int k0 = ks * 32 + (lane >> 4) * 8;
            u16x8 v;
#pragma unroll
            for (int j = 0; j < 8; ++j) v[j] = f2bf((nloc == 0) ? att[k0 + j] : 0.f);
            *reinterpret_cast<u16x8*>(attp + ((size_t)ks * 64 + lane) * 8) = v;
        }
    } else if (b < PPK + PCV) {
        const int i = ((b - PPK) * 256 + tid) * 4;
        const float4 v = *reinterpret_cast<const float4*>(met + i);
        u16x4 o; o[0] = f2bf(v.x); o[1] = f2bf(v.y); o[2] = f2bf(v.z); o[3] = f2bf(v.w);
        *reinterpret_cast<u16x4*>(metb + i) = o;
    } else {
        const int i = (b - PPK - PCV) * 256 + tid;
        if (i < EE / 4) {
            const int4 d = *reinterpret_cast<const int4*>(ei + EE + i * 4);
            atomicAdd(&cnt[d.x], 1); atomicAdd(&cnt[d.y], 1);
            atomicAdd(&cnt[d.z], 1); atomicAdd(&cnt[d.w], 1);
        }
    }
}

// ---------------- Sort by dst: 3-phase scan -> scatter -------------------
__global__ __launch_bounds__(256) void k_scan1(
    const int* __restrict__ cnt, int* __restrict__ bsum)
{
    const int i = blockIdx.x * 256 + threadIdx.x;
    int v = (i < NN) ? cnt[i] : 0;
#pragma unroll
    for (int o = 1; o < 64; o <<= 1) v += __shfl_xor(v, o);
    __shared__ int ws[4];
    if ((threadIdx.x & 63) == 0) ws[threadIdx.x >> 6] = v;
    __syncthreads();
    if (threadIdx.x == 0) bsum[blockIdx.x] = ws[0] + ws[1] + ws[2] + ws[3];
}

__global__ __launch_bounds__(512) void k_scan2(int* __restrict__ bsum)
{
    __shared__ int s[512];
    const int t = threadIdx.x;
    const int v = (t < GS) ? bsum[t] : 0;
    s[t] = v;
    __syncthreads();
    for (int o = 1; o < 512; o <<= 1) {
        const int u = (t >= o) ? s[t - o] : 0;
        __syncthreads();
        s[t] += u;
        __syncthreads();
    }
    if (t < GS) bsum[t] = s[t] - v;             // exclusive
}

__global__ __launch_bounds__(256) void k_scan3(
    const int* __restrict__ cnt, const int* __restrict__ bsum,
    int* __restrict__ cur)
{
    const int t = threadIdx.x;
    const int i = blockIdx.x * 256 + t;
    const int lane = t & 63, w = t >> 6;
    const int v = (i < NN) ? cnt[i] : 0;
    int x = v;
#pragma unroll
    for (int o = 1; o < 64; o <<= 1) {
        const int u = __shfl_up(x, o);
        if (lane >= o) x += u;
    }
    __shared__ int wsum[4];
    if (lane == 63) wsum[w] = x;
    __syncthreads();
    int off = bsum[blockIdx.x];
    for (int k2 = 0; k2 < w; ++k2) off += wsum[k2];
    if (i < NN) cur[i] = off + x - v;           // exclusive prefix
}

__global__ __launch_bounds__(256) void k_scatter(
    const int* __restrict__ ei, int* __restrict__ cur, int2* __restrict__ sd)
{
    const int i = blockIdx.x * 256 + threadIdx.x;
    if (i < EE) {
        const int d = ei[EE + i];
        const int pos = atomicAdd(&cur[d], 1);
        sd[pos] = make_int2(ei[i], d);
    }
}

// ---------------- K3: fused MLP; 64 edges/block, 8 waves (r13 structure) -
// + bijective XCD swizzle (m204): tiles are dst-sorted, so giving each XCD
// a contiguous tile window makes crb gathers / dout atomics L2-local.
__global__ __launch_bounds__(512, 6) void k_edge_mlp(
    const int2* __restrict__ sd,
    const u16* __restrict__ clb, const u16* __restrict__ crb,
    const u16* __restrict__ metb, const u16* __restrict__ attp,
    float* __restrict__ sb,
    const u16* __restrict__ W1p, const float* __restrict__ b1,
    const u16* __restrict__ W2p, const float* __restrict__ b2,
    float* __restrict__ dout)
{
    __shared__ __align__(16) char Xs[ET * 768];   // X [64][384]bf16 / H / msg-tile
    __shared__ int esrc[ET], edst[ET], flg[ET];
    __shared__ float exs[ET];

    const int tid  = threadIdx.x;
    const int wave = tid >> 6;
    const int lane = tid & 63;
    const int wm = wave >> 2, wn = wave & 3;

    // bijective XCD swizzle: nwg = 15625 = 8*1953 + 1 (q=1953, r=1)
    const int nwg = EE / ET, q = nwg >> 3, rr_ = nwg & 7;
    const int xcd = blockIdx.x & 7, io = blockIdx.x >> 3;
    const int T = (xcd < rr_ ? xcd * (q + 1) : rr_ * (q + 1) + (xcd - rr_) * q) + io;
    const int ebase = T * ET;                     // EE % ET == 0: no tail

    if (tid < ET) {
        const int2 p = sd[ebase + tid];
        esrc[tid] = p.x;
        edst[tid] = p.y;
    }
    __syncthreads();

    // ---- X-build: batch gathers, then convert+store (swizzled bf16)
    u16x8 rv[4], lv[4], mv[2];
#pragma unroll
    for (int i = 0; i < 4; ++i) {
        const int k = tid + i * 512;
        const int t = k >> 5, c = k & 31;
        rv[i] = *reinterpret_cast<const u16x8*>(crb + (size_t)edst[t] * CCH + c * 8);
        lv[i] = *reinterpret_cast<const u16x8*>(clb + (size_t)esrc[t] * CCH + c * 8);
    }
#pragma unroll
    for (int i = 0; i < 2; ++i) {
        const int k = tid + i * 512;
        mv[i] = *reinterpret_cast<const u16x8*>(metb + (size_t)esrc[k >> 4] * DMC + (k & 15) * 8);
    }
#pragma unroll
    for (int i = 0; i < 4; ++i) {
        const int k = tid + i * 512;
        const int t = k >> 5, c = k & 31;
        u16x8 v;
#pragma unroll
        for (int j = 0; j < 8; ++j) v[j] = f2bf(selu_f(bf2f(rv[i][j]) + bf2f(lv[i][j])));
        *reinterpret_cast<u16x8*>(Xs + t * 768 + ((c * 16) ^ ((t & 7) << 4))) = v;
    }
#pragma unroll
    for (int i = 0; i < 2; ++i) {
        const int k = tid + i * 512;
        const int t = k >> 4, g = k & 15;
        unsigned ob = 0;
#pragma unroll
        for (int j = 0; j < 8; ++j) ob |= (unsigned)mv[i][j];
        const bool nz = (ob & 0x7fffu) != 0u;
        const unsigned long long bal = __ballot(nz);
        if ((lane & 15) == 0)
            flg[t] = (int)((bal >> ((lane >> 4) * 16)) & 0xFFFFull) != 0;
        *reinterpret_cast<u16x8*>(Xs + t * 768 + (((32 + g) * 16) ^ ((t & 7) << 4))) = mv[i];
    }
    __syncthreads();

    const int r16   = lane & 15;
    const int khalf = (lane >> 4) << 4;
    const int rbase = (lane >> 4) * 4;

    // ---- GEMM1: H = selu(X @ W1 + b1); + alpha tile on wn==0 waves
    f32x4 acc[2][3];
    f32x4 acc3[2];
#pragma unroll
    for (int m = 0; m < 2; ++m) {
#pragma unroll
        for (int j = 0; j < 3; ++j) acc[m][j] = (f32x4){0.f, 0.f, 0.f, 0.f};
        acc3[m] = (f32x4){0.f, 0.f, 0.f, 0.f};
    }

    for (int ks = 0; ks < 12; ++ks) {
        bf16x8 b[3];
#pragma unroll
        for (int j = 0; j < 3; ++j)
            b[j] = *reinterpret_cast<const bf16x8*>(
                W1p + (((size_t)(wn + 4 * j) * 12 + ks) * 64 + lane) * 8);
        bf16x8 b3 = {};
        const bool doA = (wn == 0) && (ks < 8);
        if (doA)
            b3 = *reinterpret_cast<const bf16x8*>(attp + ((size_t)ks * 64 + lane) * 8);
        const int kb = ks * 64 + khalf;
#pragma unroll
        for (int m = 0; m < 2; ++m) {
            const int row = (wm * 2 + m) * 16 + r16;
            const bf16x8 a = *reinterpret_cast<const bf16x8*>(
                Xs + row * 768 + (kb ^ ((row & 7) << 4)));
#pragma unroll
            for (int j = 0; j < 3; ++j)
                acc[m][j] = __builtin_amdgcn_mfma_f32_16x16x32_bf16(a, b[j], acc[m][j], 0, 0, 0);
            if (doA)
                acc3[m] = __builtin_amdgcn_mfma_f32_16x16x32_bf16(a, b3, acc3[m], 0, 0, 0);
        }
    }

    // alpha extraction: col 0 of tile 12 -> lanes with (lane&15)==0
    if (wn == 0 && r16 == 0) {
        const int hi = lane >> 4;
#pragma unroll
        for (int m = 0; m < 2; ++m)
#pragma unroll
            for (int r = 0; r < 4; ++r) {
                const int e = (wm * 2 + m) * 16 + hi * 4 + r;
                const float al = acc3[m][r];
                exs[e] = (flg[e] && al != 0.f) ? __expf(al) : 0.f;
            }
    }
    __syncthreads();   // X/exs settle before overwrite with H

    // ---- write H (bf16, swizzled, row stride 384B)
#pragma unroll
    for (int j = 0; j < 3; ++j) {
        const int n = (wn + 4 * j) * 16 + r16;
        const float bb = b1[n];
#pragma unroll
        for (int m = 0; m < 2; ++m)
#pragma unroll
            for (int r = 0; r < 4; ++r) {
                const int row = (wm * 2 + m) * 16 + rbase + r;
                *reinterpret_cast<u16*>(Xs + row * 384 + ((n * 2) ^ ((row & 7) << 4))) =
                    f2bf(selu_f(acc[m][j][r] + bb));
            }
    }
    __syncthreads();

    // ---- GEMM2: F = selu(H @ W2 + b2)
    f32x4 acc2[2][2];
#pragma unroll
    for (int m = 0; m < 2; ++m)
#pragma unroll
        for (int j = 0; j < 2; ++j) acc2[m][j] = (f32x4){0.f, 0.f, 0.f, 0.f};

    for (int ks = 0; ks < 6; ++ks) {
        bf16x8 b[2];
#pragma unroll
        for (int j = 0; j < 2; ++j)
            b[j] = *reinterpret_cast<const bf16x8*>(
                W2p + (((size_t)(wn + 4 * j) * 6 + ks) * 64 + lane) * 8);
        const int kb = ks * 64 + khalf;
#pragma unroll
        for (int m = 0; m < 2; ++m) {
            const int row = (wm * 2 + m) * 16 + r16;
            const bf16x8 a = *reinterpret_cast<const bf16x8*>(
                Xs + row * 384 + (kb ^ ((row & 7) << 4)));
#pragma unroll
            for (int j = 0; j < 2; ++j)
                acc2[m][j] = __builtin_amdgcn_mfma_f32_16x16x32_bf16(a, b[j], acc2[m][j], 0, 0, 0);
        }
    }
    __syncthreads();   // all H reads done before Xs is reused as msg tile

    // ---- epilogue: msg tile (+ex col 128) to LDS, dst-segment reduce
    float* Ms = (float*)Xs;                       // [ET][MS] f32, 33.8KB
#pragma unroll
    for (int j = 0; j < 2; ++j) {
        const int n = (wn + 4 * j) * 16 + r16;
        const float bb = b2[n];
#pragma unroll
        for (int m = 0; m < 2; ++m)
#pragma unroll
            for (int r = 0; r < 4; ++r) {
                const int e = (wm * 2 + m) * 16 + rbase + r;
                Ms[e * MS + n] = selu_f(acc2[m][j][r] + bb) * exs[e];
            }
    }
    if (tid < ET) Ms[tid * MS + 128] = exs[tid];
    __syncthreads();

    {
        const int col = tid & 127;
        const int h = tid >> 7;                   // 0..3: rows [h*16, h*16+16)
        const int r0 = h * 16;
        int cur_d = edst[r0];
        float s = Ms[r0 * MS + col];
        for (int r = r0 + 1; r < r0 + 16; ++r) {
            const int d = edst[r];
            const float v = Ms[r * MS + col];
            if (d != cur_d) {
                if (s != 0.f) atomicAdd(&dout[(size_t)cur_d * OUTC + col], s);
                cur_d = d; s = v;
            } else {
                s += v;
            }
        }
        if (s != 0.f) atomicAdd(&dout[(size_t)cur_d * OUTC + col], s);
    }
    if (tid < 4) {                                // ex segment-reduce -> sb
        const int r0 = tid * 16;
        int cur_d = edst[r0];
        float s = Ms[r0 * MS + 128];
        for (int r = r0 + 1; r < r0 + 16; ++r) {
            const int d = edst[r];
            const float v = Ms[r * MS + 128];
            if (d != cur_d) {
                if (s != 0.f) atomicAdd(&sb[cur_d], s);
                cur_d = d; s = v;
            } else {
                s += v;
            }
        }
        if (s != 0.f) atomicAdd(&sb[cur_d], s);
    }
}

// ---------------- K4: finalize: divide by sum, overwrite-or-sigmoid ------
__global__ __launch_bounds__(256) void k_finalize(
    float* __restrict__ dout, const float* __restrict__ met,
    const float* __restrict__ bias, const float* __restrict__ sb)
{
    const int n = blockIdx.x * 4 + (threadIdx.x >> 6);
    const int lane = threadIdx.x & 63;
    const float a0 = dout[(size_t)n * OUTC + lane];
    const float a1 = dout[(size_t)n * OUTC + 64 + lane];
    const bool ovr = __all((a0 == 0.f) && (a1 == 0.f));
    float r0, r1;
    if (ovr) {
        r0 = met[(size_t)n * DMC + lane];
        r1 = met[(size_t)n * DMC + 64 + lane];
    } else {
        const float inv = 1.0f / (sb[n] + 1e-16f);
        r0 = 1.f / (1.f + __expf(-(a0 * inv + bias[lane])));
        r1 = 1.f / (1.f + __expf(-(a1 * inv + bias[64 + lane])));
    }
    dout[(size_t)n * OUTC + lane] = r0;
    dout[(size_t)n * OUTC + 64 + lane] = r1;
}

extern "C" void kernel_launch(void* const* d_in, const int* in_sizes, int n_in,
                              void* d_out, int out_size, void* d_ws, size_t ws_size,
                              hipStream_t stream)
{
    const int*   ei   = (const int*)d_in[0];
    const float* ss   = (const float*)d_in[1];
    const float* se   = (const float*)d_in[2];
    const float* ctx  = (const float*)d_in[3];
    const float* met  = (const float*)d_in[4];
    const float* Wl   = (const float*)d_in[5];
    const float* bl   = (const float*)d_in[6];
    const float* Wr   = (const float*)d_in[7];
    const float* br   = (const float*)d_in[8];
    const float* att  = (const float*)d_in[9];
    const float* W1   = (const float*)d_in[10];
    const float* b1   = (const float*)d_in[11];
    const float* W2   = (const float*)d_in[12];
    const float* b2   = (const float*)d_in[13];
    const float* bias = (const float*)d_in[14];

    u16* clb  = (u16*)d_ws;
    u16* crb  = clb  + (size_t)NN * CCH;
    u16* metb = crb  + (size_t)NN * CCH;
    u16* W1p  = metb + (size_t)NN * DMC;
    u16* W2p  = W1p  + (size_t)(CCH + DMC) * HDC;
    u16* W0p  = W2p  + (size_t)HDC * OUTC;
    float* sb = (float*)(W0p + (size_t)CCH * 512);
    int* cnt  = (int*)(sb + NN);      // adjacent to sb: one fused memset
    int* cur  = cnt + NN;
    int2* sd  = (int2*)(cur + NN);
    int* bsum = (int*)(sd + EE);
    u16* attp = (u16*)(bsum + 512);

    float* dout = (float*)d_out;

    hipMemsetAsync(dout, 0, (size_t)NN * OUTC * sizeof(float), stream);
    hipMemsetAsync(sb, 0, (size_t)NN * 2 * sizeof(float), stream);  // sb + cnt

    // fused pack + convert + histogram
    k_prep<<<PPK + PCV + PHS, 256, 0, stream>>>(Wl, Wr, W1, W2, att, met, ei,
                                                W0p, W1p, W2p, attp, metb, cnt);

    // dst-sort: coalesced 3-phase scan -> scatter packed pairs
    k_scan1<<<GS, 256, 0, stream>>>(cnt, bsum);
    k_scan2<<<1, 512, 0, stream>>>(bsum);
    k_scan3<<<GS, 256, 0, stream>>>(cnt, bsum, cur);
    k_scatter<<<(EE + 255) / 256, 256, 0, stream>>>(ei, cur, sd);

    k_node_gemm<<<(NN + 63) / 64, 256, 0, stream>>>(ss, se, ctx, W0p, bl, br, clb, crb);
    k_edge_mlp<<<EE / ET, 512, 0, stream>>>(sd, clb, crb, metb, attp, sb,
                                            W1p, b1, W2p, b2, dout);
    k_finalize<<<NN / 4, 256, 0, stream>>>(dout, met, bias, sb);
}